// Round 7
// baseline (502.906 us; speedup 1.0000x reference)
//
#include <hip/hip_runtime.h>

#define NEG_SLOPE 0.2f
#define CHUNK 8192      // edges per bin-block (391 blocks: full CU coverage)
#define KMAX  1600      // max buckets (N <= 102400)
#define CAP   3264      // max edges per 64-node bucket (mean 2048, sigma 45)
#define NBLKMAX 512     // max chunks (E <= 4.19M)

// ---- pass A: chunk-local counting sort by dst-bucket, stream-in/scatter-out ----
// ssrc[i] = src | (dl<<17)  (src < 2^17, dl = dst&63), seat[i] = eattr, both in
// bucket-sorted order within the chunk. cloff row = per-chunk exclusive bucket offsets.
// v7 restructure (k_bin was 101 us, VALUBusy 2.8%, FETCH 196 vs 77 MB ideal):
//  - no s_eid staging: rank kept in registers, store phase scatters directly
//  - src/eattr reads fully coalesced streams; scattered WRITES are fire-and-
//    forget and L2-merged in the chunk's 160 KB window (vs latency-bound
//    scattered reads before)
//  - block-wide scan (512 thr, 4 buckets each) replaces wave0-only serial scan
//  - LDS 72 KB -> 8.5 KB, grid 196 -> 391 blocks
__global__ __launch_bounds__(512) void k_bin(const int* __restrict__ ei,
                                             const float* __restrict__ eattr,
                                             int* __restrict__ cloff,
                                             int* __restrict__ ssrc,
                                             float4* __restrict__ seat,
                                             int E, int K) {
    __shared__ int s_off[KMAX + 1];
    __shared__ int s_scan[512];
    int t = threadIdx.x;
    for (int i = t; i <= K; i += 512) s_off[i] = 0;
    __syncthreads();
    int base = blockIdx.x * CHUNK;
    int Ec = min(CHUNK, E - base);
    unsigned pack[CHUNK / 512];
    // phase 1: count + rank (b: 11b, dl: 6b, r: 13b)
#pragma unroll
    for (int i = 0; i < CHUNK / 512; i++) {
        int el = t + 512 * i;
        pack[i] = 0xFFFFFFFFu;
        if (el < Ec) {
            int dst = ei[E + base + el];
            int b = dst >> 6;
            int r = atomicAdd(&s_off[b], 1);
            pack[i] = ((unsigned)b << 20) | ((unsigned)(dst & 63) << 14) | (unsigned)r;
        }
    }
    __syncthreads();
    // phase 2: block-wide exclusive scan of s_off[0..K] (4 buckets per thread)
    int v4[4];
    int sum = 0;
    int b0 = t << 2;
#pragma unroll
    for (int jj = 0; jj < 4; jj++) {
        int b = b0 + jj;
        int x = (b <= K) ? s_off[b] : 0;
        v4[jj] = sum;
        sum += x;
    }
    s_scan[t] = sum;
    __syncthreads();
    for (int off = 1; off < 512; off <<= 1) {
        int x = (t >= off) ? s_scan[t - off] : 0;
        __syncthreads();
        s_scan[t] += x;
        __syncthreads();
    }
    int tb = s_scan[t] - sum;
#pragma unroll
    for (int jj = 0; jj < 4; jj++) {
        int b = b0 + jj;
        if (b <= K) s_off[b] = tb + v4[jj];   // each bucket written only by its owner
    }
    __syncthreads();
    // phase 3: stream src/eattr in edge order (coalesced), scatter to sorted pos
#pragma unroll
    for (int i = 0; i < CHUNK / 512; i++) {
        int el = t + 512 * i;
        if (el < Ec) {
            unsigned p = pack[i];
            int b = p >> 20;
            int dl = (p >> 14) & 63;
            int r = p & 0x3FFF;
            int pos = s_off[b] + r;
            int e = base + el;
            int src = ei[e];
            float4 a = *(const float4*)(eattr + 4ll * e);
            ssrc[base + pos] = src | (dl << 17);
            seat[base + pos] = a;
        }
    }
    // write chunk-local offset row (contiguous)
    for (int i = t; i <= K; i += 512)
        cloff[(long long)blockIdx.x * (K + 1) + i] = s_off[i];
}

// ---- transpose cloff [NBLK][K+1] -> cloffT [K+1][NBLK] ----
__global__ void k_transp(const int* __restrict__ in, int* __restrict__ out, int R, int C) {
    __shared__ int tile[32][33];
    int c0 = blockIdx.x * 32, r0 = blockIdx.y * 32;
    int c = c0 + threadIdx.x, r = r0 + threadIdx.y;
    if (r < R && c < C) tile[threadIdx.y][threadIdx.x] = in[(long long)r * C + c];
    __syncthreads();
    int oc = r0 + threadIdx.x, orr = c0 + threadIdx.y;
    if (orr < C && oc < R) out[(long long)orr * R + oc] = tile[threadIdx.x][threadIdx.y];
}

// ---- per-bucket totals from cloffT rows ----
__global__ void k_btot(const int* __restrict__ cloffT, int* __restrict__ bucketTotal,
                       int K, int NBLK) {
    int b = (blockIdx.x * blockDim.x + threadIdx.x) >> 6;
    int lane = threadIdx.x & 63;
    if (b >= K) return;
    const int* r0 = cloffT + (long long)b * NBLK;
    const int* r1 = r0 + NBLK;
    int s = 0;
    for (int c = lane; c < NBLK; c += 64) s += r1[c] - r0[c];
#pragma unroll
    for (int off = 32; off >= 1; off >>= 1) s += __shfl_xor(s, off, 64);
    if (lane == 0) bucketTotal[b] = s;
}

// ---- scan bucket slot counts -> slotBase ----
__global__ void k_scanK(const int* __restrict__ bucketTotal, int* __restrict__ slotBase,
                        int* __restrict__ qofs, int N, int K) {
    __shared__ int s[512];
    int t = threadIdx.x;
    int v[4];
    int sum = 0;
    int base = t * 4;
    for (int j = 0; j < 4; j++) {
        int b = base + j, x = 0;
        if (b < K) { int nb = min(64, N - (b << 6)); x = bucketTotal[b] + nb; }
        v[j] = sum;
        sum += x;
    }
    s[t] = sum;
    __syncthreads();
    for (int off = 1; off < 512; off <<= 1) {
        int x = (t >= off) ? s[t - off] : 0;
        __syncthreads();
        s[t] += x;
        __syncthreads();
    }
    int tb = s[t] - sum;
    for (int j = 0; j < 4; j++) {
        int b = base + j;
        if (b < K) slotBase[b] = tb + v[j];
    }
    if (t == 511) { slotBase[K] = s[511]; qofs[4ll * N] = s[511]; }
}

// ---- pass B: per-bucket segment gather -> (dst, src-quarter)-sort -> final CSR ----
// 256-bin counting sort: bin = dl*4 + q, q = src/QDIV. Each dst's edge run is
// src-quarter-ordered (kept for potential explicit phasing; costs nothing).
__global__ __launch_bounds__(512, 8) void k_perm(const int* __restrict__ ssrc,
                                                 const float4* __restrict__ seat,
                                                 const int* __restrict__ cloffT,
                                                 const int* __restrict__ slotBase,
                                                 int* __restrict__ qofs,
                                                 int* __restrict__ fsrc,
                                                 float4* __restrict__ feat,
                                                 int N, int K, int NBLK, int QDIV) {
    __shared__ int s_pack[CAP];
    __shared__ int s_g[CAP];
    __shared__ int co[NBLKMAX], qq[NBLKMAX + 1], sc[NBLKMAX];
    __shared__ int hist2[256], cur2[256], lst2[256], sc2[256];
    __shared__ int hist[64];
    __shared__ float lsum[64][4];
    int b = blockIdx.x, t = threadIdx.x;
    int nb = min(64, N - (b << 6));
    if (t < 256) { hist2[t] = 0; cur2[t] = 0; }
    if (t < 64) {
        lsum[t][0] = 0.f; lsum[t][1] = 0.f; lsum[t][2] = 0.f; lsum[t][3] = 0.f;
    }
    const int* r0 = cloffT + (long long)b * NBLK;
    const int* r1 = r0 + NBLK;
    int len = 0;
    if (t < NBLKMAX) {
        if (t < NBLK) { int c0v = r0[t]; len = r1[t] - c0v; co[t] = c0v; }
        sc[t] = (t < NBLK) ? len : 0;
    }
    __syncthreads();
    for (int off = 1; off < NBLKMAX; off <<= 1) {
        int x = 0;
        if (t < NBLKMAX && t >= off) x = sc[t - off];
        __syncthreads();
        if (t < NBLKMAX) sc[t] += x;
        __syncthreads();
    }
    if (t < NBLK) qq[t] = sc[t] - len;
    if (t == NBLKMAX - 1) qq[NBLK] = sc[NBLKMAX - 1];
    __syncthreads();
    int Eb = qq[NBLK];
    // phase 1: gather pack words into LDS, histogram by (dl, quarter)
    for (int i = t; i < Eb; i += 512) {
        int lo2 = 0, hi2 = NBLK;
        while (lo2 + 1 < hi2) { int mid = (lo2 + hi2) >> 1; if (qq[mid] <= i) lo2 = mid; else hi2 = mid; }
        int g = lo2 * CHUNK + co[lo2] + (i - qq[lo2]);
        int p = ssrc[g];
        int srcv = p & 0x1FFFF;
        int q = (unsigned)srcv / (unsigned)QDIV;
        s_pack[i] = p | (q << 23);
        s_g[i] = g;
        atomicAdd(&hist2[(((p >> 17) & 63) << 2) | q], 1);
    }
    __syncthreads();
    // pure-edge per-dl counts (for self-loop mean), then add self-loop to its bin
    if (t < 64) {
        int c = hist2[4 * t] + hist2[4 * t + 1] + hist2[4 * t + 2] + hist2[4 * t + 3];
        hist[t] = c;
        if (t < nb) {
            int node = (b << 6) + t;
            int qs = (unsigned)node / (unsigned)QDIV;
            hist2[t * 4 + qs] += 1;           // own bins only: no race
            cur2[t * 4 + qs] = 1;             // self occupies rank 0 of its bin
        }
    }
    __syncthreads();
    // exclusive scan of hist2 over 256 bins
    if (t < 256) sc2[t] = hist2[t];
    __syncthreads();
    for (int off = 1; off < 256; off <<= 1) {
        int x = 0;
        if (t < 256 && t >= off) x = sc2[t - off];
        __syncthreads();
        if (t < 256) sc2[t] += x;
        __syncthreads();
    }
    if (t < 256) lst2[t] = sc2[t] - hist2[t];
    __syncthreads();
    int lo = slotBase[b];
    // write per-(dst, quarter) absolute offsets
    if (t < 256) {
        int dl = t >> 2;
        if (dl < nb)
            qofs[(((long long)((b << 6) + dl)) << 2) + (t & 3)] = lo + lst2[t];
    }
    // phase 3: permute to final slots, eattr global->global + LDS sums
    for (int i = t; i < Eb; i += 512) {
        int p = s_pack[i];
        int dl = (p >> 17) & 63;
        int q = (p >> 23) & 3;
        int srcv = p & 0x1FFFF;
        int bin = (dl << 2) | q;
        int r = atomicAdd(&cur2[bin], 1);
        float4 a = seat[s_g[i]];
        long long pos = lo + lst2[bin] + r;
        fsrc[pos] = srcv;
        feat[pos] = a;
        atomicAdd(&lsum[dl][0], a.x);
        atomicAdd(&lsum[dl][1], a.y);
        atomicAdd(&lsum[dl][2], a.z);
        atomicAdd(&lsum[dl][3], a.w);
    }
    __syncthreads();
    // self-loop slot: mean of incoming eattr (0 if isolated)
    if (t < nb) {
        int node = (b << 6) + t;
        int qs = (unsigned)node / (unsigned)QDIV;
        float inv = 1.f / fmaxf((float)hist[t], 1.f);
        long long pos = lo + lst2[t * 4 + qs];
        fsrc[pos] = node;
        feat[pos] = make_float4(lsum[t][0] * inv, lsum[t][1] * inv,
                                lsum[t][2] * inv, lsum[t][3] * inv);
    }
}

// ---------------- node transforms: xl = x@Wl, xr = x@Wr ----------------
template <int DIN, int D>
__global__ void k_xform(const float* __restrict__ x, const float* __restrict__ Wl,
                        const float* __restrict__ Wr, float* __restrict__ xl,
                        float* __restrict__ xr, int N) {
    __shared__ float sWl[DIN * D], sWr[DIN * D];
    for (int i = threadIdx.x; i < DIN * D; i += blockDim.x) { sWl[i] = Wl[i]; sWr[i] = Wr[i]; }
    __syncthreads();
    int t = blockIdx.x * blockDim.x + threadIdx.x;
    if (t >= N * D) return;
    int n = t / D, d = t % D;
    const float* xp = x + (long long)n * DIN;
    float sl = 0.f, sr = 0.f;
#pragma unroll
    for (int k = 0; k < DIN; k++) {
        float xv = xp[k];
        sl += xv * sWl[k * D + d];
        sr += xv * sWr[k * D + d];
    }
    xl[t] = sl;
    xr[t] = sr;
}

// ---------------- fused GATv2 layer: wave per dst, float4 per lane ----------------
// Round-3 structure (measured 100.4 us L1): pair-unroll with clamped singles.
template <int L>
__device__ __forceinline__ void gat_edge(bool valid, const float4& a, const float4& xlv,
                                         const float4& we0, const float4& we1,
                                         const float4& we2, const float4& we3,
                                         const float4& av, const float4& xrv,
                                         float4& acc, float& z) {
    float4 v;
    v.x = fmaf(a.x, we0.x, xrv.x); v.x = fmaf(a.y, we1.x, v.x);
    v.x = fmaf(a.z, we2.x, v.x);   v.x = fmaf(a.w, we3.x, v.x); v.x += xlv.x;
    v.y = fmaf(a.x, we0.y, xrv.y); v.y = fmaf(a.y, we1.y, v.y);
    v.y = fmaf(a.z, we2.y, v.y);   v.y = fmaf(a.w, we3.y, v.y); v.y += xlv.y;
    v.z = fmaf(a.x, we0.z, xrv.z); v.z = fmaf(a.y, we1.z, v.z);
    v.z = fmaf(a.z, we2.z, v.z);   v.z = fmaf(a.w, we3.z, v.z); v.z += xlv.z;
    v.w = fmaf(a.x, we0.w, xrv.w); v.w = fmaf(a.y, we1.w, v.w);
    v.w = fmaf(a.z, we2.w, v.w);   v.w = fmaf(a.w, we3.w, v.w); v.w += xlv.w;
    v.x = v.x > 0.f ? v.x : NEG_SLOPE * v.x;
    v.y = v.y > 0.f ? v.y : NEG_SLOPE * v.y;
    v.z = v.z > 0.f ? v.z : NEG_SLOPE * v.z;
    v.w = v.w > 0.f ? v.w : NEG_SLOPE * v.w;
    float sc = av.x * v.x + av.y * v.y + av.z * v.z + av.w * v.w;
#pragma unroll
    for (int off = L / 2; off >= 1; off >>= 1) sc += __shfl_xor(sc, off, 64);
    float ev = valid ? __expf(sc) : 0.f;
    z += ev;
    acc.x = fmaf(ev, xlv.x, acc.x);
    acc.y = fmaf(ev, xlv.y, acc.y);
    acc.z = fmaf(ev, xlv.z, acc.z);
    acc.w = fmaf(ev, xlv.w, acc.w);
}

template <int D, bool RELU>
__global__ void k_gat(const int* __restrict__ fsrc,
                      const float4* __restrict__ feat,
                      const int* __restrict__ qofs,
                      const float* __restrict__ xl, const float* __restrict__ xr,
                      const float* __restrict__ We, const float* __restrict__ att,
                      const float* __restrict__ bias, float* __restrict__ out, int N) {
    constexpr int L = D / 4;   // lanes per edge
    constexpr int G = 64 / L;  // edges per stage
    int w = (blockIdx.x * blockDim.x + threadIdx.x) >> 6;
    int lane = threadIdx.x & 63;
    if (w >= N) return;
    int g = lane / L;
    int j = lane % L;
    int s0 = qofs[4 * w], s1 = qofs[4 * w + 4];
    int cnt = s1 - s0;    // >= 1 (self-loop)

    const float4 we0 = *(const float4*)(We + 0 * D + 4 * j);
    const float4 we1 = *(const float4*)(We + 1 * D + 4 * j);
    const float4 we2 = *(const float4*)(We + 2 * D + 4 * j);
    const float4 we3 = *(const float4*)(We + 3 * D + 4 * j);
    const float4 av  = *(const float4*)(att + 4 * j);
    const float4 xrv = *(const float4*)(xr + (long long)w * D + 4 * j);

    float4 acc = make_float4(0.f, 0.f, 0.f, 0.f);
    float z = 0.f;

    int it = 0;
    // ---- pair stages (all lanes valid): 2 independent xl gathers in flight ----
    for (; (it + 2) * G <= cnt; it += 2) {
        int sl = s0 + it * G + g;
        int srcA = fsrc[sl];
        int srcB = fsrc[sl + G];
        float4 aA = feat[sl];
        float4 aB = feat[sl + G];
        float4 xA = *(const float4*)(xl + (long long)srcA * D + 4 * j);
        float4 xB = *(const float4*)(xl + (long long)srcB * D + 4 * j);
        gat_edge<L>(true, aA, xA, we0, we1, we2, we3, av, xrv, acc, z);
        gat_edge<L>(true, aB, xB, we0, we1, we2, we3, av, xrv, acc, z);
    }
    // ---- remaining (<=2) single stages, clamped predication ----
    for (; it * G < cnt; ++it) {
        int o = it * G + g;
        bool v = o < cnt;
        int sl = s0 + min(o, cnt - 1);
        int src = fsrc[sl];
        float4 a = feat[sl];
        float4 xv = *(const float4*)(xl + (long long)src * D + 4 * j);
        gat_edge<L>(v, a, xv, we0, we1, we2, we3, av, xrv, acc, z);
    }

#pragma unroll
    for (int off = 32; off >= L; off >>= 1) {
        acc.x += __shfl_xor(acc.x, off, 64);
        acc.y += __shfl_xor(acc.y, off, 64);
        acc.z += __shfl_xor(acc.z, off, 64);
        acc.w += __shfl_xor(acc.w, off, 64);
        z += __shfl_xor(z, off, 64);
    }

    if (g == 0) {
        float inv = 1.0f / z;
        float4 bv = *(const float4*)(bias + 4 * j);
        float4 o;
        o.x = acc.x * inv + bv.x;
        o.y = acc.y * inv + bv.y;
        o.z = acc.z * inv + bv.z;
        o.w = acc.w * inv + bv.w;
        if (RELU) {
            o.x = fmaxf(o.x, 0.f); o.y = fmaxf(o.y, 0.f);
            o.z = fmaxf(o.z, 0.f); o.w = fmaxf(o.w, 0.f);
        }
        *(float4*)(out + (long long)w * D + 4 * j) = o;
    }
}

extern "C" void kernel_launch(void* const* d_in, const int* in_sizes, int n_in,
                              void* d_out, int out_size, void* d_ws, size_t ws_size,
                              hipStream_t stream) {
    const float* x     = (const float*)d_in[0];
    const int*   ei    = (const int*)d_in[1];
    const float* eattr = (const float*)d_in[2];
    const float* Wl1   = (const float*)d_in[3];
    const float* Wr1   = (const float*)d_in[4];
    const float* We1   = (const float*)d_in[5];
    const float* att1  = (const float*)d_in[6];
    const float* b1    = (const float*)d_in[7];
    const float* Wl2   = (const float*)d_in[8];
    const float* Wr2   = (const float*)d_in[9];
    const float* We2   = (const float*)d_in[10];
    const float* att2  = (const float*)d_in[11];
    const float* b2    = (const float*)d_in[12];

    const int N = in_sizes[0] / 8;   // 100000
    const int E = in_sizes[1] / 2;   // 3200000
    const int K = (N + 63) >> 6;     // 64-node dst buckets (1563)
    const int NBLK = (E + CHUNK - 1) / CHUNK;   // 391 (<= NBLKMAX)
    const int QDIV = (N + 3) / 4;    // src-slab width (25000 nodes)

    // -------- workspace layout (4B words) --------
    int* iws = (int*)d_ws;
    size_t o = 0;
    int* bucketTotal = iws + o; o += K;
    int* slotBase    = iws + o; o += K + 1;
    int* qofs        = iws + o; o += 4ll * N + 1;
    int* cloff       = iws + o; o += (size_t)NBLK * (K + 1);
    int* cloffT      = iws + o; o += (size_t)(K + 1) * NBLK;
    o = (o + 7) & ~(size_t)7;                              // 32B align
    int*    fsrc = (int*)(iws + o);    o += (size_t)(E + N);
    o = (o + 3) & ~(size_t)3;                              // 16B align
    float4* feat = (float4*)(iws + o); o += 4ll * (E + N);
    // staging region: ssrc+seat, dead after k_perm -> reused for xl/xr/h
    size_t stage = o;
    int*    ssrc = (int*)(iws + o);    o += (size_t)E;
    o = (o + 3) & ~(size_t)3;
    float4* seat = (float4*)(iws + o); o += 4ll * E;
    float* xl = (float*)(iws + stage);           // 32N floats
    float* xr = xl + 32ll * N;
    float* h  = xr + 32ll * N;

    const int B = 256;
    auto cdiv = [](long long a, long long b) { return (int)((a + b - 1) / b); };

    // -------- CSR build: chunk-sort -> (dst, src-quarter) segment permute --------
    k_bin<<<NBLK, 512, 0, stream>>>(ei, eattr, cloff, ssrc, seat, E, K);
    dim3 tb(32, 32);
    k_transp<<<dim3(cdiv(K + 1, 32), cdiv(NBLK, 32)), tb, 0, stream>>>(cloff, cloffT, NBLK, K + 1);
    k_btot<<<cdiv(64ll * K, B), B, 0, stream>>>(cloffT, bucketTotal, K, NBLK);
    k_scanK<<<1, 512, 0, stream>>>(bucketTotal, slotBase, qofs, N, K);
    k_perm<<<K, 512, 0, stream>>>(ssrc, seat, cloffT, slotBase, qofs, fsrc, feat, N, K, NBLK, QDIV);

    // -------- layer 1 (D=32) --------
    k_xform<8, 32><<<cdiv(32ll * N, B), B, 0, stream>>>(x, Wl1, Wr1, xl, xr, N);
    k_gat<32, true><<<cdiv(N, 4), B, 0, stream>>>(fsrc, feat, qofs, xl, xr, We1, att1, b1, h, N);

    // -------- layer 2 (D=16) --------
    k_xform<32, 16><<<cdiv(16ll * N, B), B, 0, stream>>>(h, Wl2, Wr2, xl, xr, N);
    k_gat<16, false><<<cdiv(N, 4), B, 0, stream>>>(fsrc, feat, qofs, xl, xr, We2, att2, b2, (float*)d_out, N);
}

// Round 9
// 458.179 us; speedup vs baseline: 1.0976x; 1.0976x over previous
//
#include <hip/hip_runtime.h>

#define NEG_SLOPE 0.2f
#define CHUNK 4096      // edges per bin-block (LDS holds full 20B/edge payload)
#define KMAX  512       // max 256-dst buckets (N <= 131072)
#define NBLKMAX 1024    // max chunks (E <= 4.19M)

// ---- pass A: chunk-local counting sort by 256-dst bucket, LDS-staged BOTH sides ----
// Round 6 (random reads): FETCH 196 MB. Round 7 (scattered writes): WRITE 205 MB,
// partial-line amplification L2 does NOT absorb. This version: read streams
// coalesced (edge order), scatter into LDS (s_ssrc/s_seat), write out contiguous
// (sorted order) -> both sides coalesced. Bucket = dst>>8 so chunk runs stay
// ~10.5 edges for k_perm's gather coalescing.
__global__ __launch_bounds__(1024) void k_bin(const int* __restrict__ ei,
                                              const float* __restrict__ eattr,
                                              int* __restrict__ cloff,
                                              int* __restrict__ ssrc,
                                              float4* __restrict__ seat,
                                              int E, int K) {
    __shared__ int s_off[KMAX + 1];
    __shared__ int s_scan[1024];
    __shared__ int s_ssrc[CHUNK];
    __shared__ float4 s_seat[CHUNK];
    int t = threadIdx.x;
    for (int i = t; i <= K; i += 1024) s_off[i] = 0;
    __syncthreads();
    int base = blockIdx.x * CHUNK;
    int Ec = min(CHUNK, E - base);
    unsigned pack[CHUNK / 1024];
    // phase 1: count + rank (b: 9b, dl: 8b, r: 12b)
#pragma unroll
    for (int i = 0; i < CHUNK / 1024; i++) {
        int el = t + 1024 * i;
        pack[i] = 0xFFFFFFFFu;
        if (el < Ec) {
            int dst = ei[E + base + el];
            int b = dst >> 8;
            int r = atomicAdd(&s_off[b], 1);
            pack[i] = ((unsigned)b << 20) | ((unsigned)(dst & 255) << 12) | (unsigned)r;
        }
    }
    __syncthreads();
    // phase 2: block-wide exclusive scan of s_off[0..K] (K+1 = 392 <= 1024)
    int x0 = (t <= K) ? s_off[t] : 0;
    s_scan[t] = x0;
    __syncthreads();
    for (int off = 1; off < 1024; off <<= 1) {
        int y = (t >= off) ? s_scan[t - off] : 0;
        __syncthreads();
        s_scan[t] += y;
        __syncthreads();
    }
    if (t <= K) s_off[t] = s_scan[t] - x0;   // exclusive
    __syncthreads();
    // phase 3: stream src/eattr coalesced (edge order), scatter into LDS at sorted pos
#pragma unroll
    for (int i = 0; i < CHUNK / 1024; i++) {
        int el = t + 1024 * i;
        if (el < Ec) {
            unsigned p = pack[i];
            int b = p >> 20;
            int dl = (p >> 12) & 255;
            int r = p & 0xFFF;
            int pos = s_off[b] + r;
            int e = base + el;
            s_ssrc[pos] = ei[e] | (dl << 17);
            s_seat[pos] = *(const float4*)(eattr + 4ll * e);
        }
    }
    __syncthreads();
    // phase 4: contiguous coalesced write-out (sorted order)
    for (int pos = t; pos < Ec; pos += 1024) {
        ssrc[base + pos] = s_ssrc[pos];
        seat[base + pos] = s_seat[pos];
    }
    for (int i = t; i <= K; i += 1024)
        cloff[(long long)blockIdx.x * (K + 1) + i] = s_off[i];
}

// ---- transpose cloff [NBLK][K+1] -> cloffT [K+1][NBLK] ----
__global__ void k_transp(const int* __restrict__ in, int* __restrict__ out, int R, int C) {
    __shared__ int tile[32][33];
    int c0 = blockIdx.x * 32, r0 = blockIdx.y * 32;
    int c = c0 + threadIdx.x, r = r0 + threadIdx.y;
    if (r < R && c < C) tile[threadIdx.y][threadIdx.x] = in[(long long)r * C + c];
    __syncthreads();
    int oc = r0 + threadIdx.x, orr = c0 + threadIdx.y;
    if (orr < C && oc < R) out[(long long)orr * R + oc] = tile[threadIdx.x][threadIdx.y];
}

// ---- per-bucket totals from cloffT rows ----
__global__ void k_btot(const int* __restrict__ cloffT, int* __restrict__ bucketTotal,
                       int K, int NBLK) {
    int b = (blockIdx.x * blockDim.x + threadIdx.x) >> 6;
    int lane = threadIdx.x & 63;
    if (b >= K) return;
    const int* r0 = cloffT + (long long)b * NBLK;
    const int* r1 = r0 + NBLK;
    int s = 0;
    for (int c = lane; c < NBLK; c += 64) s += r1[c] - r0[c];
#pragma unroll
    for (int off = 32; off >= 1; off >>= 1) s += __shfl_xor(s, off, 64);
    if (lane == 0) bucketTotal[b] = s;
}

// ---- scan bucket slot counts (edges + 256 self-loops per bucket) -> slotBase ----
__global__ void k_scanK(const int* __restrict__ bucketTotal, int* __restrict__ slotBase,
                        int* __restrict__ qofs, int N, int K) {
    __shared__ int s[512];
    int t = threadIdx.x;
    int v[4];
    int sum = 0;
    int base = t * 4;
    for (int j = 0; j < 4; j++) {
        int b = base + j, x = 0;
        if (b < K) { int nb = min(256, N - (b << 8)); x = bucketTotal[b] + nb; }
        v[j] = sum;
        sum += x;
    }
    s[t] = sum;
    __syncthreads();
    for (int off = 1; off < 512; off <<= 1) {
        int x = (t >= off) ? s[t - off] : 0;
        __syncthreads();
        s[t] += x;
        __syncthreads();
    }
    int tb = s[t] - sum;
    for (int j = 0; j < 4; j++) {
        int b = base + j;
        if (b < K) slotBase[b] = tb + v[j];
    }
    if (t == 511) { slotBase[K] = s[511]; qofs[4ll * N] = s[511]; }
}

// ---- pass B: per-bucket (256 dsts) segment gather -> (dst,quarter)-sort -> CSR ----
// No staged pack/g arrays (capacity-free): g recomputed via second binary search,
// ssrc re-read is L2-hot. 1024 bins = dl*4+q. Self-loop = rank 0 of its own bin.
__global__ __launch_bounds__(1024, 2) void k_perm(const int* __restrict__ ssrc,
                                                  const float4* __restrict__ seat,
                                                  const int* __restrict__ cloffT,
                                                  const int* __restrict__ slotBase,
                                                  int* __restrict__ qofs,
                                                  int* __restrict__ fsrc,
                                                  float4* __restrict__ feat,
                                                  int N, int K, int NBLK, int QDIV) {
    __shared__ int co[NBLKMAX], qq[NBLKMAX + 1], sc[NBLKMAX];
    __shared__ int hist2[1024], cur2[1024], lst2[1024], sc2[1024];
    __shared__ int hist[256];
    __shared__ float lsum[256][4];
    int b = blockIdx.x, t = threadIdx.x;
    int nb = min(256, N - (b << 8));
    hist2[t] = 0; cur2[t] = 0;
    if (t < 256) { lsum[t][0] = 0.f; lsum[t][1] = 0.f; lsum[t][2] = 0.f; lsum[t][3] = 0.f; }
    const int* r0 = cloffT + (long long)b * NBLK;
    const int* r1 = r0 + NBLK;
    int len = 0;
    if (t < NBLK) { int c0v = r0[t]; len = r1[t] - c0v; co[t] = c0v; }
    sc[t] = (t < NBLK) ? len : 0;
    __syncthreads();
    for (int off = 1; off < NBLKMAX; off <<= 1) {
        int x = (t >= off) ? sc[t - off] : 0;
        __syncthreads();
        sc[t] += x;
        __syncthreads();
    }
    if (t < NBLK) qq[t] = sc[t] - len;
    if (t == NBLKMAX - 1) qq[NBLK] = sc[NBLKMAX - 1];
    __syncthreads();
    int Eb = qq[NBLK];
    // phase 1: histogram by (dl, quarter); ssrc reads in ~10.5-edge runs
    for (int i = t; i < Eb; i += 1024) {
        int lo2 = 0, hi2 = NBLK;
        while (lo2 + 1 < hi2) { int mid = (lo2 + hi2) >> 1; if (qq[mid] <= i) lo2 = mid; else hi2 = mid; }
        int g = lo2 * CHUNK + co[lo2] + (i - qq[lo2]);
        int p = ssrc[g];
        int q = (int)((unsigned)(p & 0x1FFFF) / (unsigned)QDIV);
        atomicAdd(&hist2[(((p >> 17) & 255) << 2) | q], 1);
    }
    __syncthreads();
    // pure-edge per-dst counts (self-loop mean divisor), then seed self-loop bin
    if (t < 256) {
        int c = hist2[4 * t] + hist2[4 * t + 1] + hist2[4 * t + 2] + hist2[4 * t + 3];
        hist[t] = c;
        if (t < nb) {
            int node = (b << 8) + t;
            int qs = (int)((unsigned)node / (unsigned)QDIV);
            hist2[4 * t + qs] += 1;           // own bins only: no race
            cur2[4 * t + qs] = 1;             // self occupies rank 0 of its bin
        }
    }
    __syncthreads();
    // exclusive scan of hist2 over 1024 bins
    sc2[t] = hist2[t];
    __syncthreads();
    for (int off = 1; off < 1024; off <<= 1) {
        int x = (t >= off) ? sc2[t - off] : 0;
        __syncthreads();
        sc2[t] += x;
        __syncthreads();
    }
    lst2[t] = sc2[t] - hist2[t];
    __syncthreads();
    int lo = slotBase[b];
    // per-(dst,quarter) absolute offsets: qofs[4*node+q] = qofs[(b<<10)+t]
    if (t < 4 * nb) qofs[((long long)b << 10) + t] = lo + lst2[t];
    // phase 3: permute to final slots (recompute g), eattr runs ~168 B
    for (int i = t; i < Eb; i += 1024) {
        int lo2 = 0, hi2 = NBLK;
        while (lo2 + 1 < hi2) { int mid = (lo2 + hi2) >> 1; if (qq[mid] <= i) lo2 = mid; else hi2 = mid; }
        int g = lo2 * CHUNK + co[lo2] + (i - qq[lo2]);
        int p = ssrc[g];
        int srcv = p & 0x1FFFF;
        int dl = (p >> 17) & 255;
        int q = (int)((unsigned)srcv / (unsigned)QDIV);
        int bin = (dl << 2) | q;
        int r = atomicAdd(&cur2[bin], 1);
        float4 a = seat[g];
        long long pos = lo + lst2[bin] + r;
        fsrc[pos] = srcv;
        feat[pos] = a;
        atomicAdd(&lsum[dl][0], a.x);
        atomicAdd(&lsum[dl][1], a.y);
        atomicAdd(&lsum[dl][2], a.z);
        atomicAdd(&lsum[dl][3], a.w);
    }
    __syncthreads();
    // self-loop slot: mean of incoming eattr (0 if isolated)
    if (t < nb) {
        int node = (b << 8) + t;
        int qs = (int)((unsigned)node / (unsigned)QDIV);
        float inv = 1.f / fmaxf((float)hist[t], 1.f);
        long long pos = lo + lst2[4 * t + qs];
        fsrc[pos] = node;
        feat[pos] = make_float4(lsum[t][0] * inv, lsum[t][1] * inv,
                                lsum[t][2] * inv, lsum[t][3] * inv);
    }
}

// ---------------- node transforms: xl = x@Wl, xr = x@Wr ----------------
template <int DIN, int D>
__global__ void k_xform(const float* __restrict__ x, const float* __restrict__ Wl,
                        const float* __restrict__ Wr, float* __restrict__ xl,
                        float* __restrict__ xr, int N) {
    __shared__ float sWl[DIN * D], sWr[DIN * D];
    for (int i = threadIdx.x; i < DIN * D; i += blockDim.x) { sWl[i] = Wl[i]; sWr[i] = Wr[i]; }
    __syncthreads();
    int t = blockIdx.x * blockDim.x + threadIdx.x;
    if (t >= N * D) return;
    int n = t / D, d = t % D;
    const float* xp = x + (long long)n * DIN;
    float sl = 0.f, sr = 0.f;
#pragma unroll
    for (int k = 0; k < DIN; k++) {
        float xv = xp[k];
        sl += xv * sWl[k * D + d];
        sr += xv * sWr[k * D + d];
    }
    xl[t] = sl;
    xr[t] = sr;
}

// ---------------- fused GATv2 layer: wave per dst, float4 per lane ----------------
// Round-3 structure (measured 100.4 us L1): pair-unroll with clamped singles.
template <int L>
__device__ __forceinline__ void gat_edge(bool valid, const float4& a, const float4& xlv,
                                         const float4& we0, const float4& we1,
                                         const float4& we2, const float4& we3,
                                         const float4& av, const float4& xrv,
                                         float4& acc, float& z) {
    float4 v;
    v.x = fmaf(a.x, we0.x, xrv.x); v.x = fmaf(a.y, we1.x, v.x);
    v.x = fmaf(a.z, we2.x, v.x);   v.x = fmaf(a.w, we3.x, v.x); v.x += xlv.x;
    v.y = fmaf(a.x, we0.y, xrv.y); v.y = fmaf(a.y, we1.y, v.y);
    v.y = fmaf(a.z, we2.y, v.y);   v.y = fmaf(a.w, we3.y, v.y); v.y += xlv.y;
    v.z = fmaf(a.x, we0.z, xrv.z); v.z = fmaf(a.y, we1.z, v.z);
    v.z = fmaf(a.z, we2.z, v.z);   v.z = fmaf(a.w, we3.z, v.z); v.z += xlv.z;
    v.w = fmaf(a.x, we0.w, xrv.w); v.w = fmaf(a.y, we1.w, v.w);
    v.w = fmaf(a.z, we2.w, v.w);   v.w = fmaf(a.w, we3.w, v.w); v.w += xlv.w;
    v.x = v.x > 0.f ? v.x : NEG_SLOPE * v.x;
    v.y = v.y > 0.f ? v.y : NEG_SLOPE * v.y;
    v.z = v.z > 0.f ? v.z : NEG_SLOPE * v.z;
    v.w = v.w > 0.f ? v.w : NEG_SLOPE * v.w;
    float sc = av.x * v.x + av.y * v.y + av.z * v.z + av.w * v.w;
#pragma unroll
    for (int off = L / 2; off >= 1; off >>= 1) sc += __shfl_xor(sc, off, 64);
    float ev = valid ? __expf(sc) : 0.f;
    z += ev;
    acc.x = fmaf(ev, xlv.x, acc.x);
    acc.y = fmaf(ev, xlv.y, acc.y);
    acc.z = fmaf(ev, xlv.z, acc.z);
    acc.w = fmaf(ev, xlv.w, acc.w);
}

template <int D, bool RELU>
__global__ void k_gat(const int* __restrict__ fsrc,
                      const float4* __restrict__ feat,
                      const int* __restrict__ qofs,
                      const float* __restrict__ xl, const float* __restrict__ xr,
                      const float* __restrict__ We, const float* __restrict__ att,
                      const float* __restrict__ bias, float* __restrict__ out, int N) {
    constexpr int L = D / 4;   // lanes per edge
    constexpr int G = 64 / L;  // edges per stage
    int w = (blockIdx.x * blockDim.x + threadIdx.x) >> 6;
    int lane = threadIdx.x & 63;
    if (w >= N) return;
    int g = lane / L;
    int j = lane % L;
    int s0 = qofs[4 * w], s1 = qofs[4 * w + 4];
    int cnt = s1 - s0;    // >= 1 (self-loop)

    const float4 we0 = *(const float4*)(We + 0 * D + 4 * j);
    const float4 we1 = *(const float4*)(We + 1 * D + 4 * j);
    const float4 we2 = *(const float4*)(We + 2 * D + 4 * j);
    const float4 we3 = *(const float4*)(We + 3 * D + 4 * j);
    const float4 av  = *(const float4*)(att + 4 * j);
    const float4 xrv = *(const float4*)(xr + (long long)w * D + 4 * j);

    float4 acc = make_float4(0.f, 0.f, 0.f, 0.f);
    float z = 0.f;

    int it = 0;
    // ---- pair stages (all lanes valid): 2 independent xl gathers in flight ----
    for (; (it + 2) * G <= cnt; it += 2) {
        int sl = s0 + it * G + g;
        int srcA = fsrc[sl];
        int srcB = fsrc[sl + G];
        float4 aA = feat[sl];
        float4 aB = feat[sl + G];
        float4 xA = *(const float4*)(xl + (long long)srcA * D + 4 * j);
        float4 xB = *(const float4*)(xl + (long long)srcB * D + 4 * j);
        gat_edge<L>(true, aA, xA, we0, we1, we2, we3, av, xrv, acc, z);
        gat_edge<L>(true, aB, xB, we0, we1, we2, we3, av, xrv, acc, z);
    }
    // ---- remaining (<=2) single stages, clamped predication ----
    for (; it * G < cnt; ++it) {
        int o = it * G + g;
        bool v = o < cnt;
        int sl = s0 + min(o, cnt - 1);
        int src = fsrc[sl];
        float4 a = feat[sl];
        float4 xv = *(const float4*)(xl + (long long)src * D + 4 * j);
        gat_edge<L>(v, a, xv, we0, we1, we2, we3, av, xrv, acc, z);
    }

#pragma unroll
    for (int off = 32; off >= L; off >>= 1) {
        acc.x += __shfl_xor(acc.x, off, 64);
        acc.y += __shfl_xor(acc.y, off, 64);
        acc.z += __shfl_xor(acc.z, off, 64);
        acc.w += __shfl_xor(acc.w, off, 64);
        z += __shfl_xor(z, off, 64);
    }

    if (g == 0) {
        float inv = 1.0f / z;
        float4 bv = *(const float4*)(bias + 4 * j);
        float4 o;
        o.x = acc.x * inv + bv.x;
        o.y = acc.y * inv + bv.y;
        o.z = acc.z * inv + bv.z;
        o.w = acc.w * inv + bv.w;
        if (RELU) {
            o.x = fmaxf(o.x, 0.f); o.y = fmaxf(o.y, 0.f);
            o.z = fmaxf(o.z, 0.f); o.w = fmaxf(o.w, 0.f);
        }
        *(float4*)(out + (long long)w * D + 4 * j) = o;
    }
}

extern "C" void kernel_launch(void* const* d_in, const int* in_sizes, int n_in,
                              void* d_out, int out_size, void* d_ws, size_t ws_size,
                              hipStream_t stream) {
    const float* x     = (const float*)d_in[0];
    const int*   ei    = (const int*)d_in[1];
    const float* eattr = (const float*)d_in[2];
    const float* Wl1   = (const float*)d_in[3];
    const float* Wr1   = (const float*)d_in[4];
    const float* We1   = (const float*)d_in[5];
    const float* att1  = (const float*)d_in[6];
    const float* b1    = (const float*)d_in[7];
    const float* Wl2   = (const float*)d_in[8];
    const float* Wr2   = (const float*)d_in[9];
    const float* We2   = (const float*)d_in[10];
    const float* att2  = (const float*)d_in[11];
    const float* b2    = (const float*)d_in[12];

    const int N = in_sizes[0] / 8;   // 100000
    const int E = in_sizes[1] / 2;   // 3200000
    const int K = (N + 255) >> 8;    // 256-dst buckets (391)
    const int NBLK = (E + CHUNK - 1) / CHUNK;   // 782 (<= NBLKMAX)
    const int QDIV = (N + 3) / 4;    // src-slab width (25000 nodes)

    // -------- workspace layout (4B words) --------
    int* iws = (int*)d_ws;
    size_t o = 0;
    int* bucketTotal = iws + o; o += K;
    int* slotBase    = iws + o; o += K + 1;
    int* qofs        = iws + o; o += 4ll * N + 1;
    int* cloff       = iws + o; o += (size_t)NBLK * (K + 1);
    int* cloffT      = iws + o; o += (size_t)(K + 1) * NBLK;
    o = (o + 7) & ~(size_t)7;                              // 32B align
    int*    fsrc = (int*)(iws + o);    o += (size_t)(E + N);
    o = (o + 3) & ~(size_t)3;                              // 16B align
    float4* feat = (float4*)(iws + o); o += 4ll * (E + N);
    // staging region: ssrc+seat, dead after k_perm -> reused for xl/xr/h
    size_t stage = o;
    int*    ssrc = (int*)(iws + o);    o += (size_t)E;
    o = (o + 3) & ~(size_t)3;
    float4* seat = (float4*)(iws + o); o += 4ll * E;
    float* xl = (float*)(iws + stage);           // 32N floats
    float* xr = xl + 32ll * N;
    float* h  = xr + 32ll * N;

    const int B = 256;
    auto cdiv = [](long long a, long long b) { return (int)((a + b - 1) / b); };

    // -------- CSR build: chunk-sort (both sides coalesced) -> segment permute --------
    k_bin<<<NBLK, 1024, 0, stream>>>(ei, eattr, cloff, ssrc, seat, E, K);
    dim3 tb(32, 32);
    k_transp<<<dim3(cdiv(K + 1, 32), cdiv(NBLK, 32)), tb, 0, stream>>>(cloff, cloffT, NBLK, K + 1);
    k_btot<<<cdiv(64ll * K, B), B, 0, stream>>>(cloffT, bucketTotal, K, NBLK);
    k_scanK<<<1, 512, 0, stream>>>(bucketTotal, slotBase, qofs, N, K);
    k_perm<<<K, 1024, 0, stream>>>(ssrc, seat, cloffT, slotBase, qofs, fsrc, feat, N, K, NBLK, QDIV);

    // -------- layer 1 (D=32) --------
    k_xform<8, 32><<<cdiv(32ll * N, B), B, 0, stream>>>(x, Wl1, Wr1, xl, xr, N);
    k_gat<32, true><<<cdiv(N, 4), B, 0, stream>>>(fsrc, feat, qofs, xl, xr, We1, att1, b1, h, N);

    // -------- layer 2 (D=16) --------
    k_xform<32, 16><<<cdiv(16ll * N, B), B, 0, stream>>>(h, Wl2, Wr2, xl, xr, N);
    k_gat<16, false><<<cdiv(N, 4), B, 0, stream>>>(fsrc, feat, qofs, xl, xr, We2, att2, b2, (float*)d_out, N);
}